// Round 4
// baseline (183.656 us; speedup 1.0000x reference)
//
#include <hip/hip_runtime.h>

#define NDOM 8
#define TT   32      // tile dim (rows == cols)
#define KDIM 1024    // feature dim, fixed by harness (setup_inputs: 4096x1024)
#define BMAX 4096    // batch, fixed by harness

typedef float f32x4 __attribute__((ext_vector_type(4)));

struct Ctrl {
    unsigned bar0;      // grid barrier (gather -> gram)
    unsigned bar1;      // completion counter (gram -> finalize)
    unsigned pad[6];
    float ps[NDOM];     // per-domain pair sums
};

__device__ inline void gload16(const void* g, void* l) {
    __builtin_amdgcn_global_load_lds(
        (const __attribute__((address_space(1))) unsigned int*)g,
        (__attribute__((address_space(3))) unsigned int*)l, 16, 0, 0);
}

// One fused kernel, grid = 256 blocks x 256 threads (1 block/CU, co-resident).
// Phase A: redundant label bucketing (each block), rank+gather own 16 rows
//          fp32 -> fp8(e4m3) + row norms.  Grid barrier (device-scope).
// Phase B: persistent upper-triangle 32x32 tiles, full-K LDS resident (no
//          K-loop barriers), fp8 MFMA Gram, fused relu(1-dist) epilogue.
// Phase C: last-arriving block finalizes the scalar output (no second spin).
__global__ __launch_bounds__(256) void k_fused(
    const float* __restrict__ F, const int* __restrict__ labels, int B,
    unsigned char* __restrict__ Fb, float* __restrict__ sq,
    Ctrl* __restrict__ ctrl, float* __restrict__ out) {
    __shared__ int lab[BMAX];                         // 16 KB
    __shared__ unsigned wcnt[4][NDOM];
    __shared__ int s_dst[64];
    __shared__ int s_offs[NDOM + 1], s_ts[NDOM + 1];
    __shared__ __align__(16) unsigned char lA[TT * KDIM];  // 32 KB
    __shared__ __align__(16) unsigned char lB[TT * KDIM];  // 32 KB

    const int t = threadIdx.x, lane = t & 63, wv = t >> 6;
    const int b = blockIdx.x, nb = gridDim.x;

    // ---------------- phase A0: labels -> LDS (padded with -1) ----------------
    for (int i = t; i < BMAX; i += 256) lab[i] = (i < B) ? labels[i] : -1;
    __syncthreads();

    // ---------------- phase A1: counts via ballot/popc ----------------
    int nch = (B + 63) >> 6;
    int cpw = (nch + 3) >> 2;
    int ca = wv * cpw, cb = min(ca + cpw, nch);
    unsigned cnt[NDOM];
#pragma unroll
    for (int d = 0; d < NDOM; ++d) cnt[d] = 0;
    for (int c = ca; c < cb; ++c) {
        int d = lab[c * 64 + lane];
#pragma unroll
        for (int dd = 0; dd < NDOM; ++dd)
            cnt[dd] += (unsigned)__popcll(__ballot(d == dd));
    }
    if (lane == 0)
#pragma unroll
        for (int dd = 0; dd < NDOM; ++dd) wcnt[wv][dd] = cnt[dd];
    __syncthreads();

    unsigned offs[NDOM + 1];
    offs[0] = 0;
#pragma unroll
    for (int dd = 0; dd < NDOM; ++dd)
        offs[dd + 1] = offs[dd] + wcnt[0][dd] + wcnt[1][dd] + wcnt[2][dd] + wcnt[3][dd];
    if (t == 0) {
        int T = 0;
#pragma unroll
        for (int d = 0; d < NDOM; ++d) {
            s_offs[d] = (int)offs[d];
            s_ts[d] = T;
            int n = (int)(offs[d + 1] - offs[d]);
            int nt = (n + TT - 1) / TT;
            T += nt * (nt + 1) / 2;
        }
        s_offs[NDOM] = (int)offs[NDOM];
        s_ts[NDOM] = T;
    }

    // ---------------- phase A2: rank own sources (wave 0) ----------------
    const int rpb = (B + nb - 1) / nb;   // 16 for 4096/256; fits one 64-chunk
    const int i0 = b * rpb;
    if (wv == 0) {
        unsigned run[NDOM];
#pragma unroll
        for (int dd = 0; dd < NDOM; ++dd) run[dd] = offs[dd];
        int c0 = i0 >> 6;
        for (int c = 0; c < c0; ++c) {
            int d = lab[c * 64 + lane];
#pragma unroll
            for (int dd = 0; dd < NDOM; ++dd)
                run[dd] += (unsigned)__popcll(__ballot(d == dd));
        }
        int d = lab[c0 * 64 + lane];
        unsigned long long below = (1ull << lane) - 1ull;
        int base = i0 & 63;
        int pos = -1;
#pragma unroll
        for (int dd = 0; dd < NDOM; ++dd) {
            unsigned long long m = __ballot(d == dd);
            if (d == dd) pos = (int)run[dd] + __popcll(m & below);
        }
        if (lane >= base && lane < base + rpb) s_dst[lane - base] = pos;
    }
    __syncthreads();

    // ---------------- phase A3: gather + fp32->fp8 + norms ----------------
    for (int j = wv; j < rpb; j += 4) {
        int src = i0 + j;
        if (src >= B) break;
        int dst = s_dst[j];
        const float4* srow = (const float4*)(F + (size_t)src * KDIM);
        int* drow = (int*)(Fb + (size_t)dst * KDIM);
        float ss = 0.f;
#pragma unroll
        for (int jj = 0; jj < 4; ++jj) {
            float4 v = srow[jj * 64 + lane];
            ss += v.x * v.x + v.y * v.y + v.z * v.z + v.w * v.w;
            int p = __builtin_amdgcn_cvt_pk_fp8_f32(v.x, v.y, 0, false);
            p = __builtin_amdgcn_cvt_pk_fp8_f32(v.z, v.w, p, true);
            drow[jj * 64 + lane] = p;
        }
#pragma unroll
        for (int s = 32; s > 0; s >>= 1) ss += __shfl_xor(ss, s);
        if (lane == 0) sq[dst] = ss;
    }

    // ---------------- grid barrier (device-scope, all 256 blocks resident) ----
    __syncthreads();                       // drains vmcnt: stores at L2
    if (t == 0) {
        __threadfence();                   // agent release: writeback dirty L2
        atomicAdd(&ctrl->bar0, 1u);
        while (__hip_atomic_load(&ctrl->bar0, __ATOMIC_ACQUIRE,
                                 __HIP_MEMORY_SCOPE_AGENT) < (unsigned)nb)
            __builtin_amdgcn_s_sleep(2);
        __threadfence();                   // agent acquire: invalidate stale
    }
    __syncthreads();

    // ---------------- phase B: upper-triangle 32x32 tiles, full-K ----------
    const int T = s_ts[NDOM];
    const int m16 = lane & 15, quad = lane >> 4;
    const int wm = (wv & 1) * 16, wn = (wv >> 1) * 16;
    const int hs = (quad & 1) * 8;         // byte half within 16B chunk
    const int cbase = quad >> 1;           // chunk addend per ks

    for (int tile = b; tile < T; tile += nb) {
        int dom = 0;
        while (tile >= s_ts[dom + 1]) ++dom;
        int off = s_offs[dom], n = s_offs[dom + 1] - off;
        int nt = (n + TT - 1) / TT;
        int rel = tile - s_ts[dom];
        int ty = 0, rem = rel;
        while (rem >= nt - ty) { rem -= nt - ty; ++ty; }
        int tx = ty + rem;
        int tr = ty * TT, tc = tx * TT;
        bool diag = (ty == tx);

        // stage: wave wv rows wv*8..+8; 1 row = 1 KB = 64 lanes x 16B.
        // XOR swizzle on the GLOBAL chunk index (LDS dst stays uniform+lane*16)
#pragma unroll
        for (int j = 0; j < 8; ++j) {
            int r = wv * 8 + j;
            int c = lane ^ (r & 15);
            const unsigned char* ga =
                Fb + (size_t)(off + min(tr + r, n - 1)) * KDIM + c * 16;
            gload16(ga, lA + r * KDIM);
            if (!diag) {
                const unsigned char* gb =
                    Fb + (size_t)(off + min(tc + r, n - 1)) * KDIM + c * 16;
                gload16(gb, lB + r * KDIM);
            }
        }
        __syncthreads();   // single drain per tile

        const unsigned char* Bbuf = diag ? lA : lB;
        const int rA = wm + m16, rB = wn + m16;
        const int xA = rA & 15, xB = rB & 15;
        f32x4 acc = (f32x4){0.f, 0.f, 0.f, 0.f};
#pragma unroll
        for (int ks = 0; ks < 32; ++ks) {
            int cc = ks * 2 + cbase;
            long a = *(const long*)(lA + rA * KDIM + ((cc ^ xA) * 16 + hs));
            long bbv = *(const long*)(Bbuf + rB * KDIM + ((cc ^ xB) * 16 + hs));
            acc = __builtin_amdgcn_mfma_f32_16x16x32_fp8_fp8(a, bbv, acc, 0, 0, 0);
        }

        // epilogue: C[row=quad*4+r][col=m16]; diag val exactly 1.0
        float local = 0.f;
        int pr0 = tr + wm + quad * 4;
        int pc = tc + wn + m16;
        if (pc < n) {
            float sb = sq[off + pc];
#pragma unroll
            for (int r = 0; r < 4; ++r) {
                int pr = pr0 + r;
                if (pr < n) {
                    float val;
                    if (pr == pc) {
                        val = 1.0f;
                    } else {
                        float d2 = sq[off + pr] + sb - 2.0f * acc[r];
                        d2 = fmaxf(d2, 0.f);
                        val = fmaxf(1.0f - sqrtf(d2), 0.f);
                    }
                    local += val;
                }
            }
        }
        if (!diag) local *= 2.f;
#pragma unroll
        for (int s = 32; s > 0; s >>= 1) local += __shfl_xor(local, s);
        if (lane == 0) atomicAdd(&ctrl->ps[dom], local);
        __syncthreads();   // all reads done before next tile's staging
    }

    // ---------------- phase C: last block finalizes ----------------
    __syncthreads();       // drains vmcnt: this block's ps atomics committed
    if (t == 0) {
        __threadfence();
        unsigned old = atomicAdd(&ctrl->bar1, 1u);
        if (old == (unsigned)nb - 1) {
            __threadfence();
            float s = 0.f;
            int v = 0;
            for (int d = 0; d < NDOM; ++d) {
                int n = s_offs[d + 1] - s_offs[d];
                if (n > 1) {
                    float p = __hip_atomic_load(&ctrl->ps[d], __ATOMIC_RELAXED,
                                                __HIP_MEMORY_SCOPE_AGENT);
                    s += p / ((float)n * (float)n);
                    ++v;
                }
            }
            out[0] = (v > 0) ? s / (float)v : 0.f;
        }
    }
}

// ---------------------------------------------------------------- launch ----
extern "C" void kernel_launch(void* const* d_in, const int* in_sizes, int n_in,
                              void* d_out, int out_size, void* d_ws, size_t ws_size,
                              hipStream_t stream) {
    const float* F = (const float*)d_in[0];
    const int* labels = (const int*)d_in[1];
    int B = in_sizes[1];                 // 4096

    char* ws = (char*)d_ws;
    Ctrl* ctrl = (Ctrl*)ws;
    unsigned char* Fb = (unsigned char*)(ws + 4096);
    float* sq = (float*)(ws + 4096 + (size_t)B * KDIM);

    hipMemsetAsync(ctrl, 0, 128, stream);
    k_fused<<<256, 256, 0, stream>>>(F, labels, B, Fb, sq, ctrl, (float*)d_out);
}

// Round 5
// 154.459 us; speedup vs baseline: 1.1890x; 1.1890x over previous
//
#include <hip/hip_runtime.h>

#define NDOM 8
#define TT   32      // tile dim
#define KDIM 1024    // feature dim (harness-fixed)
#define RPAD 1040    // LDS row stride: 1024 + 16 pad -> 260 dwords -> 4-bank skew
#define BMAX 4096    // batch (harness-fixed)

typedef float f32x4 __attribute__((ext_vector_type(4)));

struct Ctrl {
    unsigned bar;       // gram completion counter
    unsigned pad[7];
    float ps[NDOM];     // per-domain pair sums
};

__device__ inline void gload16(const void* g, void* l) {
    __builtin_amdgcn_global_load_lds(
        (const __attribute__((address_space(1))) unsigned int*)g,
        (__attribute__((address_space(3))) unsigned int*)l, 16, 0, 0);
}

__device__ inline unsigned short f2bf(float f) { return (unsigned short)(__float_as_uint(f) >> 16); }

// ------------------------------------------------------------------ prep ----
// Block 0: label bucketing (ballot/popc, LDS-staged labels) -> perm, dom_off;
//          zeroes ctrl. Blocks 1..: fp32 -> fp8(e4m3) convert IN ORIGINAL
//          ORDER (no perm dependency -> runs concurrently) + row norms.
__global__ __launch_bounds__(256) void k_prep(
    const float* __restrict__ F, const int* __restrict__ labels, int B,
    unsigned char* __restrict__ Fb, float* __restrict__ sq,
    int* __restrict__ perm, int* __restrict__ dom_off, Ctrl* __restrict__ ctrl) {
    const int t = threadIdx.x, lane = t & 63, wv = t >> 6;

    if (blockIdx.x == 0) {
        // ---- bucket (proven R3 scheme) ----
        __shared__ int lab[BMAX];
        __shared__ unsigned wcnt[4][NDOM];
        for (int i = t; i < BMAX; i += 256) lab[i] = (i < B) ? labels[i] : -1;
        __syncthreads();

        int nch = (B + 63) >> 6;
        int cpw = (nch + 3) >> 2;
        int c0 = wv * cpw, c1 = min(c0 + cpw, nch);
        unsigned long long below = (1ull << lane) - 1ull;

        unsigned cnt[NDOM];
#pragma unroll
        for (int d = 0; d < NDOM; ++d) cnt[d] = 0;
        for (int c = c0; c < c1; ++c) {
            int d = lab[c * 64 + lane];
#pragma unroll
            for (int dd = 0; dd < NDOM; ++dd)
                cnt[dd] += (unsigned)__popcll(__ballot(d == dd));
        }
        if (lane == 0)
#pragma unroll
            for (int dd = 0; dd < NDOM; ++dd) wcnt[wv][dd] = cnt[dd];
        __syncthreads();

        unsigned offs[NDOM + 1];
        offs[0] = 0;
#pragma unroll
        for (int dd = 0; dd < NDOM; ++dd)
            offs[dd + 1] = offs[dd] + wcnt[0][dd] + wcnt[1][dd] + wcnt[2][dd] + wcnt[3][dd];
        if (t < NDOM) ctrl->ps[t] = 0.f;
        if (t == NDOM) ctrl->bar = 0u;
        if (t <= NDOM) dom_off[t] = (int)offs[t];

        unsigned run[NDOM];
#pragma unroll
        for (int dd = 0; dd < NDOM; ++dd) {
            unsigned base = offs[dd];
            for (int w = 0; w < 4; ++w)
                if (w < wv) base += wcnt[w][dd];
            run[dd] = base;
        }
        for (int c = c0; c < c1; ++c) {
            int i = c * 64 + lane;
            int d = lab[i];
            int pos = -1;
#pragma unroll
            for (int dd = 0; dd < NDOM; ++dd) {
                unsigned long long m = __ballot(d == dd);
                if (d == dd) pos = (int)run[dd] + __popcll(m & below);
                run[dd] += (unsigned)__popcll(m);
            }
            if (i < B) perm[pos] = i;
        }
        return;
    }

    // ---- convert: 16 rows per block, 4 rows per wave, original order ----
    int i0 = (int)(blockIdx.x - 1) * 16;
    for (int j = wv; j < 16; j += 4) {
        int row = i0 + j;
        if (row >= B) break;
        const float4* srow = (const float4*)(F + (size_t)row * KDIM);
        int* drow = (int*)(Fb + (size_t)row * KDIM);
        float ss = 0.f;
#pragma unroll
        for (int it = 0; it < 4; ++it) {
            float4 v = srow[it * 64 + lane];
            ss += v.x * v.x + v.y * v.y + v.z * v.z + v.w * v.w;
            int p = __builtin_amdgcn_cvt_pk_fp8_f32(v.x, v.y, 0, false);
            p = __builtin_amdgcn_cvt_pk_fp8_f32(v.z, v.w, p, true);
            drow[it * 64 + lane] = p;
        }
#pragma unroll
        for (int s = 32; s > 0; s >>= 1) ss += __shfl_xor(ss, s);
        if (lane == 0) sq[row] = ss;
    }
}

// ------------------------------------------------------------------ gram ----
// Upper-triangle 32x32 fp8 tiles, full-K LDS-resident (1 staging drain/tile).
// Staging: one global_load_lds per row, lanes LINEAR (coalesced 1 KB);
// LDS rows padded to 1040 B (between-instruction padding) -> ds_read_b64
// fragment reads are <=2-way bank aliased (free). Rows indirected via perm.
__global__ __launch_bounds__(256) void k_gram(
    const unsigned char* __restrict__ Fb, const float* __restrict__ sq,
    const int* __restrict__ perm, const int* __restrict__ dom_off,
    Ctrl* __restrict__ ctrl, float* __restrict__ out) {
    __shared__ __align__(16) unsigned char lA[TT * RPAD];  // 32.5 KB
    __shared__ __align__(16) unsigned char lB[TT * RPAD];  // 32.5 KB
    __shared__ int s_p[64];
    __shared__ float s_sq[64];
    __shared__ int s_offs[NDOM + 1], s_ts[NDOM + 1];

    const int t = threadIdx.x, lane = t & 63, wv = t >> 6;
    const int m16 = lane & 15, quad = lane >> 4;
    const int wm = (wv & 1) * 16, wn = (wv >> 1) * 16;

    if (t == 0) {
        int T = 0;
        for (int d = 0; d < NDOM; ++d) {
            int o0 = dom_off[d], o1 = dom_off[d + 1];
            s_offs[d] = o0;
            s_ts[d] = T;
            int n = o1 - o0;
            int nt = (n + TT - 1) / TT;
            T += nt * (nt + 1) / 2;
        }
        s_offs[NDOM] = dom_off[NDOM];
        s_ts[NDOM] = T;
    }
    __syncthreads();
    const int T = s_ts[NDOM];

    for (int tile = blockIdx.x; tile < T; tile += gridDim.x) {
        int dom = 0;
        while (tile >= s_ts[dom + 1]) ++dom;
        int off = s_offs[dom], n = s_offs[dom + 1] - off;
        int nt = (n + TT - 1) / TT;
        int rel = tile - s_ts[dom];
        int ty = 0, rem = rel;
        while (rem >= nt - ty) { rem -= nt - ty; ++ty; }
        int tx = ty + rem;
        int tr = ty * TT, tc = tx * TT;
        bool diag = (ty == tx);

        // (a) perm + sq for the 64 tile rows/cols
        if (t < 64) {
            int r = (t < 32) ? min(tr + t, n - 1) : min(tc + (t - 32), n - 1);
            int p = perm[off + r];
            s_p[t] = p;
            s_sq[t] = sq[p];
        }
        __syncthreads();

        // (b) staging: 1 instr per row, lanes linear -> fully coalesced
#pragma unroll
        for (int j = 0; j < 16; ++j) {
            int r = wv * 16 + j;          // 0..63: A rows 0..31, B rows 32..63
            if (r < 32) {
                const unsigned char* g = Fb + (size_t)s_p[r] * KDIM + lane * 16;
                gload16(g, lA + r * RPAD);
            } else if (!diag) {
                const unsigned char* g = Fb + (size_t)s_p[r] * KDIM + lane * 16;
                gload16(g, lB + (r - 32) * RPAD);
            }
        }
        __syncthreads();   // single vmcnt drain per tile

        // (c) MFMA: two interleaved accumulators to split the dep chain
        const unsigned char* Bbuf = diag ? lA : lB;
        const unsigned char* pa = lA + (wm + m16) * RPAD + quad * 8;
        const unsigned char* pb = Bbuf + (wn + m16) * RPAD + quad * 8;
        f32x4 ac0 = (f32x4){0.f, 0.f, 0.f, 0.f};
        f32x4 ac1 = (f32x4){0.f, 0.f, 0.f, 0.f};
#pragma unroll
        for (int ks = 0; ks < 32; ks += 2) {
            long a0 = *(const long*)(pa + ks * 32);
            long b0 = *(const long*)(pb + ks * 32);
            long a1 = *(const long*)(pa + ks * 32 + 32);
            long b1 = *(const long*)(pb + ks * 32 + 32);
            ac0 = __builtin_amdgcn_mfma_f32_16x16x32_fp8_fp8(a0, b0, ac0, 0, 0, 0);
            ac1 = __builtin_amdgcn_mfma_f32_16x16x32_fp8_fp8(a1, b1, ac1, 0, 0, 0);
        }

        // (d) epilogue: C[row=quad*4+r][col=m16]; diagonal exactly 1.0
        float local = 0.f;
        int lr0 = wm + quad * 4;          // local row 0..31
        int lc = wn + m16;                // local col 0..31
        int pc = tc + lc;
        if (pc < n) {
            float sb = s_sq[32 + lc];
#pragma unroll
            for (int r = 0; r < 4; ++r) {
                int pr = tr + lr0 + r;
                if (pr < n) {
                    float val;
                    if (pr == pc) {
                        val = 1.0f;
                    } else {
                        float d2 = s_sq[lr0 + r] + sb - 2.0f * (ac0[r] + ac1[r]);
                        d2 = fmaxf(d2, 0.f);
                        val = fmaxf(1.0f - sqrtf(d2), 0.f);
                    }
                    local += val;
                }
            }
        }
        if (!diag) local *= 2.f;
#pragma unroll
        for (int s = 32; s > 0; s >>= 1) local += __shfl_xor(local, s);
        if (lane == 0) atomicAdd(&ctrl->ps[dom], local);
        __syncthreads();   // LDS reuse fence before next tile
    }

    // ---- last-arriving block finalizes (R4-proven pattern) ----
    __syncthreads();
    if (t == 0) {
        __threadfence();
        unsigned old = atomicAdd(&ctrl->bar, 1u);
        if (old == (unsigned)gridDim.x - 1) {
            __threadfence();
            float s = 0.f;
            int v = 0;
            for (int d = 0; d < NDOM; ++d) {
                int n = s_offs[d + 1] - s_offs[d];
                if (n > 1) {
                    float p = __hip_atomic_load(&ctrl->ps[d], __ATOMIC_RELAXED,
                                                __HIP_MEMORY_SCOPE_AGENT);
                    s += p / ((float)n * (float)n);
                    ++v;
                }
            }
            out[0] = (v > 0) ? s / (float)v : 0.f;
        }
    }
}

// ---------------------------------------------------------------- launch ----
extern "C" void kernel_launch(void* const* d_in, const int* in_sizes, int n_in,
                              void* d_out, int out_size, void* d_ws, size_t ws_size,
                              hipStream_t stream) {
    const float* F = (const float*)d_in[0];
    const int* labels = (const int*)d_in[1];
    int B = in_sizes[1];                 // 4096

    char* ws = (char*)d_ws;
    Ctrl* ctrl = (Ctrl*)ws;
    unsigned char* Fb = (unsigned char*)(ws + 4096);
    float* sq = (float*)(ws + 4096 + (size_t)BMAX * KDIM);
    int* perm = (int*)(ws + 4096 + (size_t)BMAX * KDIM + BMAX * 4);
    int* dom_off = (int*)(ws + 4096 + (size_t)BMAX * KDIM + BMAX * 8);

    int ncv = (B + 15) / 16;
    k_prep<<<ncv + 1, 256, 0, stream>>>(F, labels, B, Fb, sq, perm, dom_off, ctrl);
    k_gram<<<1024, 256, 0, stream>>>(Fb, sq, perm, dom_off, ctrl, (float*)d_out);
}

// Round 6
// 95.878 us; speedup vs baseline: 1.9155x; 1.6110x over previous
//
#include <hip/hip_runtime.h>

#define NDOM 8
#define TT   32      // tile dim
#define KDIM 1024    // feature dim (harness-fixed)
#define RPAD 1040    // LDS row stride: 1024 + 16 pad -> 4-bank skew per row
#define BMAX 4096    // batch (harness-fixed)
#define GGRID 512    // k_gram grid (2 blocks/CU, single residency round)

typedef float f32x4 __attribute__((ext_vector_type(4)));

__device__ inline void gload16(const void* g, void* l) {
    __builtin_amdgcn_global_load_lds(
        (const __attribute__((address_space(1))) unsigned int*)g,
        (__attribute__((address_space(3))) unsigned int*)l, 16, 0, 0);
}

// ------------------------------------------------------------------ prep ----
// Block 0: label bucketing (ballot/popc) -> perm, dom_off.
// Blocks 1..: fp32 -> fp8(e4m3) convert in ORIGINAL order + row norms.
__global__ __launch_bounds__(256) void k_prep(
    const float* __restrict__ F, const int* __restrict__ labels, int B,
    unsigned char* __restrict__ Fb, float* __restrict__ sq,
    int* __restrict__ perm, int* __restrict__ dom_off) {
    const int t = threadIdx.x, lane = t & 63, wv = t >> 6;

    if (blockIdx.x == 0) {
        __shared__ int lab[BMAX];
        __shared__ unsigned wcnt[4][NDOM];
        for (int i = t; i < BMAX; i += 256) lab[i] = (i < B) ? labels[i] : -1;
        __syncthreads();

        int nch = (B + 63) >> 6;
        int cpw = (nch + 3) >> 2;
        int c0 = wv * cpw, c1 = min(c0 + cpw, nch);
        unsigned long long below = (1ull << lane) - 1ull;

        unsigned cnt[NDOM];
#pragma unroll
        for (int d = 0; d < NDOM; ++d) cnt[d] = 0;
        for (int c = c0; c < c1; ++c) {
            int d = lab[c * 64 + lane];
#pragma unroll
            for (int dd = 0; dd < NDOM; ++dd)
                cnt[dd] += (unsigned)__popcll(__ballot(d == dd));
        }
        if (lane == 0)
#pragma unroll
            for (int dd = 0; dd < NDOM; ++dd) wcnt[wv][dd] = cnt[dd];
        __syncthreads();

        unsigned offs[NDOM + 1];
        offs[0] = 0;
#pragma unroll
        for (int dd = 0; dd < NDOM; ++dd)
            offs[dd + 1] = offs[dd] + wcnt[0][dd] + wcnt[1][dd] + wcnt[2][dd] + wcnt[3][dd];
        if (t <= NDOM) dom_off[t] = (int)offs[t];

        unsigned run[NDOM];
#pragma unroll
        for (int dd = 0; dd < NDOM; ++dd) {
            unsigned base = offs[dd];
            for (int w = 0; w < 4; ++w)
                if (w < wv) base += wcnt[w][dd];
            run[dd] = base;
        }
        for (int c = c0; c < c1; ++c) {
            int i = c * 64 + lane;
            int d = lab[i];
            int pos = -1;
#pragma unroll
            for (int dd = 0; dd < NDOM; ++dd) {
                unsigned long long m = __ballot(d == dd);
                if (d == dd) pos = (int)run[dd] + __popcll(m & below);
                run[dd] += (unsigned)__popcll(m);
            }
            if (i < B) perm[pos] = i;
        }
        return;
    }

    int i0 = (int)(blockIdx.x - 1) * 16;
    for (int j = wv; j < 16; j += 4) {
        int row = i0 + j;
        if (row >= B) break;
        const float4* srow = (const float4*)(F + (size_t)row * KDIM);
        int* drow = (int*)(Fb + (size_t)row * KDIM);
        float ss = 0.f;
#pragma unroll
        for (int it = 0; it < 4; ++it) {
            float4 v = srow[it * 64 + lane];
            ss += v.x * v.x + v.y * v.y + v.z * v.z + v.w * v.w;
            int p = __builtin_amdgcn_cvt_pk_fp8_f32(v.x, v.y, 0, false);
            p = __builtin_amdgcn_cvt_pk_fp8_f32(v.z, v.w, p, true);
            drow[it * 64 + lane] = p;
        }
#pragma unroll
        for (int s = 32; s > 0; s >>= 1) ss += __shfl_xor(ss, s);
        if (lane == 0) sq[row] = ss;
    }
}

// ------------------------------------------------------------------ gram ----
// Identical staging/MFMA/epilogue to R5; the ONLY change: per-domain sums
// accumulate in block-private LDS (ds_add_f32) and exit via plain stores to
// part[block][8]. Zero contended device-scope atomics.
__global__ __launch_bounds__(256) void k_gram(
    const unsigned char* __restrict__ Fb, const float* __restrict__ sq,
    const int* __restrict__ perm, const int* __restrict__ dom_off,
    float* __restrict__ part) {
    __shared__ __align__(16) unsigned char lA[TT * RPAD];  // 32.5 KB
    __shared__ __align__(16) unsigned char lB[TT * RPAD];  // 32.5 KB
    __shared__ int s_p[64];
    __shared__ float s_sq[64];
    __shared__ int s_offs[NDOM + 1], s_ts[NDOM + 1];
    __shared__ float s_ps[NDOM];

    const int t = threadIdx.x, lane = t & 63, wv = t >> 6;
    const int m16 = lane & 15, quad = lane >> 4;
    const int wm = (wv & 1) * 16, wn = (wv >> 1) * 16;

    if (t == 0) {
        int T = 0;
        for (int d = 0; d < NDOM; ++d) {
            int o0 = dom_off[d], o1 = dom_off[d + 1];
            s_offs[d] = o0;
            s_ts[d] = T;
            int n = o1 - o0;
            int nt = (n + TT - 1) / TT;
            T += nt * (nt + 1) / 2;
        }
        s_offs[NDOM] = dom_off[NDOM];
        s_ts[NDOM] = T;
    }
    if (t < NDOM) s_ps[t] = 0.f;
    __syncthreads();
    const int T = s_ts[NDOM];

    for (int tile = blockIdx.x; tile < T; tile += gridDim.x) {
        int dom = 0;
        while (tile >= s_ts[dom + 1]) ++dom;
        int off = s_offs[dom], n = s_offs[dom + 1] - off;
        int nt = (n + TT - 1) / TT;
        int rel = tile - s_ts[dom];
        int ty = 0, rem = rel;
        while (rem >= nt - ty) { rem -= nt - ty; ++ty; }
        int tx = ty + rem;
        int tr = ty * TT, tc = tx * TT;
        bool diag = (ty == tx);

        if (t < 64) {
            int r = (t < 32) ? min(tr + t, n - 1) : min(tc + (t - 32), n - 1);
            int p = perm[off + r];
            s_p[t] = p;
            s_sq[t] = sq[p];
        }
        __syncthreads();

#pragma unroll
        for (int j = 0; j < 16; ++j) {
            int r = wv * 16 + j;          // 0..63: A rows 0..31, B rows 32..63
            if (r < 32) {
                const unsigned char* g = Fb + (size_t)s_p[r] * KDIM + lane * 16;
                gload16(g, lA + r * RPAD);
            } else if (!diag) {
                const unsigned char* g = Fb + (size_t)s_p[r] * KDIM + lane * 16;
                gload16(g, lB + (r - 32) * RPAD);
            }
        }
        __syncthreads();   // single vmcnt drain per tile

        const unsigned char* Bbuf = diag ? lA : lB;
        const unsigned char* pa = lA + (wm + m16) * RPAD + quad * 8;
        const unsigned char* pb = Bbuf + (wn + m16) * RPAD + quad * 8;
        f32x4 ac0 = (f32x4){0.f, 0.f, 0.f, 0.f};
        f32x4 ac1 = (f32x4){0.f, 0.f, 0.f, 0.f};
#pragma unroll
        for (int ks = 0; ks < 32; ks += 2) {
            long a0 = *(const long*)(pa + ks * 32);
            long b0 = *(const long*)(pb + ks * 32);
            long a1 = *(const long*)(pa + ks * 32 + 32);
            long b1 = *(const long*)(pb + ks * 32 + 32);
            ac0 = __builtin_amdgcn_mfma_f32_16x16x32_fp8_fp8(a0, b0, ac0, 0, 0, 0);
            ac1 = __builtin_amdgcn_mfma_f32_16x16x32_fp8_fp8(a1, b1, ac1, 0, 0, 0);
        }

        float local = 0.f;
        int lr0 = wm + quad * 4;
        int lc = wn + m16;
        int pc = tc + lc;
        if (pc < n) {
            float sb = s_sq[32 + lc];
#pragma unroll
            for (int r = 0; r < 4; ++r) {
                int pr = tr + lr0 + r;
                if (pr < n) {
                    float val;
                    if (pr == pc) {
                        val = 1.0f;
                    } else {
                        float d2 = s_sq[lr0 + r] + sb - 2.0f * (ac0[r] + ac1[r]);
                        d2 = fmaxf(d2, 0.f);
                        val = fmaxf(1.0f - sqrtf(d2), 0.f);
                    }
                    local += val;
                }
            }
        }
        if (!diag) local *= 2.f;
#pragma unroll
        for (int s = 32; s > 0; s >>= 1) local += __shfl_xor(local, s);
        if (lane == 0) atomicAdd(&s_ps[dom], local);   // LDS atomic: contention-free
        __syncthreads();   // LDS reuse fence before next tile
    }

    __syncthreads();
    if (t < NDOM) part[blockIdx.x * NDOM + t] = s_ps[t];  // private slot, plain store
}

// -------------------------------------------------------------- finalize ----
// Reduce part[GGRID][8] -> per-domain sums -> scalar loss.
__global__ __launch_bounds__(256) void k_final(
    const float* __restrict__ part, const int* __restrict__ dom_off,
    float* __restrict__ out) {
    __shared__ float red[8][32];
    int t = threadIdx.x;
    int d = t & 7, ch = t >> 3;           // 32 chunks x 8 domains
    float s = 0.f;
    for (int b = ch; b < GGRID; b += 32) s += part[b * NDOM + d];
    red[d][ch] = s;
    __syncthreads();
    if (t < NDOM) {
        float ps = 0.f;
#pragma unroll
        for (int c = 0; c < 32; ++c) ps += red[t][c];
        red[t][0] = ps;
    }
    __syncthreads();
    if (t == 0) {
        float acc = 0.f;
        int v = 0;
        for (int dd = 0; dd < NDOM; ++dd) {
            int n = dom_off[dd + 1] - dom_off[dd];
            if (n > 1) {
                acc += red[dd][0] / ((float)n * (float)n);
                ++v;
            }
        }
        out[0] = (v > 0) ? acc / (float)v : 0.f;
    }
}

// ---------------------------------------------------------------- launch ----
extern "C" void kernel_launch(void* const* d_in, const int* in_sizes, int n_in,
                              void* d_out, int out_size, void* d_ws, size_t ws_size,
                              hipStream_t stream) {
    const float* F = (const float*)d_in[0];
    const int* labels = (const int*)d_in[1];
    int B = in_sizes[1];                 // 4096

    char* ws = (char*)d_ws;
    unsigned char* Fb = (unsigned char*)ws;
    float* sq = (float*)(ws + (size_t)BMAX * KDIM);
    int* perm = (int*)(ws + (size_t)BMAX * KDIM + BMAX * 4);
    int* dom_off = (int*)(ws + (size_t)BMAX * KDIM + BMAX * 8);
    float* part = (float*)(ws + (size_t)BMAX * KDIM + BMAX * 8 + 256);

    int ncv = (B + 15) / 16;
    k_prep<<<ncv + 1, 256, 0, stream>>>(F, labels, B, Fb, sq, perm, dom_off);
    k_gram<<<GGRID, 256, 0, stream>>>(Fb, sq, perm, dom_off, part);
    k_final<<<1, 256, 0, stream>>>(part, dom_off, (float*)d_out);
}